// Round 1
// baseline (365.271 us; speedup 1.0000x reference)
//
#include <hip/hip_runtime.h>
#include <math.h>

#define B_     8
#define C_H_   128
#define C_L_   256
#define K_     64
#define NPIX_L 16384          // 128*128
#define EPS_   1e-5f

// ws layout: P (float) | B1 (bf16, swizzled) | B2 (bf16, swizzled) | bias (float)
#define P_OFF     0
#define P_SZ      (B_*K_*C_H_)                 // 65536 floats
#define B1_BYTE   (P_SZ*4)                     // 262144
#define B2_BYTE   (B1_BYTE + B_*K_*C_L_*2)     // +262144
#define BIAS_BYTE (B2_BYTE + B_*K_*C_L_*2)     // 512 floats

typedef short bf16x8 __attribute__((ext_vector_type(8)));   // 4 VGPRs = 8 bf16
typedef float f32x4  __attribute__((ext_vector_type(4)));

__device__ inline unsigned short f2bf(float f) {            // RNE fp32->bf16
    unsigned int u = __float_as_uint(f);
    u += 0x7FFFu + ((u >> 16) & 1u);
    return (unsigned short)(u >> 16);
}
__device__ inline unsigned int pack2bf(float lo, float hi) { // two bf16 in one u32
    unsigned int ul = __float_as_uint(lo);
    unsigned int uh = __float_as_uint(hi);
    ul = (ul + (0x7FFFu + ((ul >> 16) & 1u))) >> 16;
    uh = (uh + (0x7FFFu + ((uh >> 16) & 1u))) & 0xFFFF0000u;
    return ul | uh;
}

#define MFMA16(a, b, c) __builtin_amdgcn_mfma_f32_16x16x32_bf16((a), (b), (c), 0, 0, 0)

// ---------------- Kernel 1: BN + 8x8 max-pool of x_h -> p[b][k][c] ----------------
// BN monotone: max(BN(x)) = BN(max x) if scale>=0 else BN(min x).
__global__ __launch_bounds__(256) void pool_bn_kernel(
    const float* __restrict__ x_h,
    const float* __restrict__ g, const float* __restrict__ be,
    const float* __restrict__ mn, const float* __restrict__ vr,
    float* __restrict__ ws)
{
    const int t   = threadIdx.x;
    const int k   = t & 63;
    const int cl  = t >> 6;
    const int bid = blockIdx.x;    // 256 = 8 b * 32 cgroups
    const int b   = bid >> 5;
    const int c   = ((bid & 31) << 2) + cl;

    const float* plane = x_h + ((size_t)(b * C_H_ + c) << 12);
    const int ph = k >> 3, pw = k & 7;
    const float* p0 = plane + (ph * 8) * 64 + pw * 8;

    float mx = -INFINITY, mnv = INFINITY;
#pragma unroll
    for (int i = 0; i < 8; i++) {
        const float4 a  = *reinterpret_cast<const float4*>(p0 + i * 64);
        const float4 bq = *reinterpret_cast<const float4*>(p0 + i * 64 + 4);
        mx  = fmaxf(mx,  fmaxf(fmaxf(a.x, a.y),  fmaxf(a.z, a.w)));
        mx  = fmaxf(mx,  fmaxf(fmaxf(bq.x, bq.y), fmaxf(bq.z, bq.w)));
        mnv = fminf(mnv, fminf(fminf(a.x, a.y),  fminf(a.z, a.w)));
        mnv = fminf(mnv, fminf(fminf(bq.x, bq.y), fminf(bq.z, bq.w)));
    }
    const float sc  = g[c] * rsqrtf(vr[c] + EPS_);
    const float sel = (sc >= 0.f) ? mx : mnv;
    ws[P_OFF + (b * K_ + k) * C_H_ + c] = fmaf(sel - mn[c], sc, be[c]);
}

// ---------------- Kernel 2: kv projection -> swizzled bf16 B1/B2 + softmax bias ----------------
// B1[c][kk] = ck[kk][c]*scl[c]  (GEMM1 B-operand, frag-linear order)
// B2[kk][co] = cv[co][kk]       (GEMM2 B-operand, frag-linear order)
// bias[b][kk] = (sum_c shf[c]*ck[kk][c] + reatt[kk]) * 0.125   (BN shift + reatt folded)
__global__ __launch_bounds__(256) void kv_kernel(
    const float* __restrict__ kv_w, const float* __restrict__ kv_b,
    const float* __restrict__ lg, const float* __restrict__ lb,
    const float* __restrict__ lm, const float* __restrict__ lv,
    const float* __restrict__ ratt,
    float* __restrict__ ws)
{
    __shared__ __align__(16) float prow[C_H_];
    __shared__ float red[4];
    const int t   = threadIdx.x;
    const int bid = blockIdx.x;          // 512 = 8 b * 64 kk
    const int b   = bid >> 6;
    const int kk  = bid & 63;

    if (t < C_H_ / 4) {
        reinterpret_cast<float4*>(prow)[t] =
            reinterpret_cast<const float4*>(ws + P_OFF + (b * K_ + kk) * C_H_)[t];
    }
    __syncthreads();

    float a0 = kv_b[t];          // ck[b][kk][c=t]
    float a1 = kv_b[t + 256];    // cv[b][co=t][kk]
    const float* w0 = kv_w + (size_t)t * C_H_;
    const float* w1 = kv_w + (size_t)(t + 256) * C_H_;
#pragma unroll
    for (int c = 0; c < C_H_; c += 4) {
        const float4 pv  = *reinterpret_cast<const float4*>(prow + c);
        const float4 wv0 = *reinterpret_cast<const float4*>(w0 + c);
        const float4 wv1 = *reinterpret_cast<const float4*>(w1 + c);
        a0 = fmaf(wv0.x, pv.x, a0); a0 = fmaf(wv0.y, pv.y, a0);
        a0 = fmaf(wv0.z, pv.z, a0); a0 = fmaf(wv0.w, pv.w, a0);
        a1 = fmaf(wv1.x, pv.x, a1); a1 = fmaf(wv1.y, pv.y, a1);
        a1 = fmaf(wv1.z, pv.z, a1); a1 = fmaf(wv1.w, pv.w, a1);
    }

    // BN-l coeffs for channel t
    const float s = lg[t] * rsqrtf(lv[t] + EPS_);
    const float h = fmaf(-lm[t], s, lb[t]);

    // block-reduce sum_c h*a0  (bias from folded BN shift)
    float contrib = h * a0;
#pragma unroll
    for (int m = 1; m < 64; m <<= 1) contrib += __shfl_xor(contrib, m, 64);
    if ((t & 63) == 0) red[t >> 6] = contrib;
    __syncthreads();

    unsigned short* b1 = (unsigned short*)((char*)ws + B1_BYTE);
    unsigned short* b2 = (unsigned short*)((char*)ws + B2_BYTE);

    {   // B1 swizzle: value at (c=t, kk): s1=c>>5, lane=((c>>3)&3)*16 + (kk&15), j=c&7, n=kk>>4
        const int s1 = t >> 5, j = t & 7;
        const int l  = ((t >> 3) & 3) * 16 + (kk & 15);
        const int n  = kk >> 4;
        b1[((((b * 8 + s1) * 4 + n) * 64) + l) * 8 + j] = f2bf(a0 * s);
    }
    {   // B2 swizzle: value at (kk, co=t): s2=kk>>5, lane=((kk>>3)&3)*16 + (t&15), j=kk&7, n=t>>4
        const int s2 = kk >> 5, j2 = kk & 7;
        const int l2 = ((kk >> 3) & 3) * 16 + (t & 15);
        const int n2 = t >> 4;
        b2[((((b * 2 + s2) * 16 + n2) * 64) + l2) * 8 + j2] = f2bf(a1);
    }
    if (t == 0) {
        float* bia = (float*)((char*)ws + BIAS_BYTE);
        bia[b * K_ + kk] = (red[0] + red[1] + red[2] + red[3] + ratt[kk]) * 0.125f;
    }
}

// ---------------- Kernel 3: MFMA attention ----------------
// 2048 blocks (b=bid&7 XCD-pinned), 256 threads = 4 waves, 16 px/wave (1 M-tile).
// 8192 waves total = 32 waves/CU -> 100% occupancy cap (was 16/CU at 32px/wave).
// GEMM1: S[16px x 64k] = X(bf16) @ B1, K=256 (8 steps). Softmax in C-layout regs.
// W -> LDS (padded stride 72) -> A-layout frags. GEMM2: Out[16px x 256c] = W @ B2, K=64.
// Epilogue residual+store is float4 (r=0..3 contiguous, 16B aligned).
// No __syncthreads: each wave owns its LDS rows.
__global__ __launch_bounds__(256, 8) void attn_mfma(
    const float* __restrict__ x_l,
    const float* __restrict__ ws_f,
    float* __restrict__ out)
{
    __shared__ unsigned short wa[64 * 72];    // 9.2 KB, +8 pad per row

    const int t    = threadIdx.x;
    const int lane = t & 63;
    const int wid  = t >> 6;
    const int bid  = blockIdx.x;
    const int b    = bid & 7;
    const int tile = bid >> 3;                 // 0..255
    const int pw0  = tile * 64 + wid * 16;     // wave's global pixel base
    const int r16  = lane & 15;
    const int q    = lane >> 4;

    const unsigned short* b1 = (const unsigned short*)((const char*)ws_f + B1_BYTE);
    const unsigned short* b2 = (const unsigned short*)((const char*)ws_f + B2_BYTE);
    const float* biasf = (const float*)((const char*)ws_f + BIAS_BYTE) + b * K_;
    const float* xb = x_l + (size_t)b * (C_L_ * NPIX_L);

    float bl[4];
#pragma unroll
    for (int n = 0; n < 4; n++) bl[n] = biasf[16 * n + r16];   // bias for kk=16n+r16

    // ---- GEMM1 ----
    f32x4 acc1[4] = {};
    union ABu { bf16x8 v; unsigned int u[4]; };
    const float* xpx = xb + pw0 + r16;

#pragma unroll
    for (int s = 0; s < 8; s++) {
        const int c0 = 32 * s + q * 8;
        float xv[8];
#pragma unroll
        for (int j = 0; j < 8; j++) {
            xv[j] = xpx[(size_t)(c0 + j) * NPIX_L];
        }
        ABu a0f;
#pragma unroll
        for (int jj = 0; jj < 4; jj++) {
            a0f.u[jj] = pack2bf(xv[2 * jj], xv[2 * jj + 1]);
        }
        const bf16x8* bp = ((const bf16x8*)b1) + ((b * 8 + s) * 4) * 64 + lane;
#pragma unroll
        for (int n = 0; n < 4; n++) {
            const bf16x8 bfr = bp[n * 64];
            acc1[n] = MFMA16(a0f.v, bfr, acc1[n]);
        }
    }

    // ---- softmax (C-layout: px = pw0 + 4q + r, kk = 16n + r16) + W -> LDS ----
    const int plbase = wid * 16;
#pragma unroll
    for (int r = 0; r < 4; r++) {
        float e0 = fmaf(acc1[0][r], 0.125f, bl[0]);
        float e1 = fmaf(acc1[1][r], 0.125f, bl[1]);
        float e2 = fmaf(acc1[2][r], 0.125f, bl[2]);
        float e3 = fmaf(acc1[3][r], 0.125f, bl[3]);
        float mx = fmaxf(fmaxf(e0, e1), fmaxf(e2, e3));
#pragma unroll
        for (int msk = 1; msk < 16; msk <<= 1) mx = fmaxf(mx, __shfl_xor(mx, msk, 64));
        e0 = __expf(e0 - mx); e1 = __expf(e1 - mx);
        e2 = __expf(e2 - mx); e3 = __expf(e3 - mx);
        float sm = (e0 + e1) + (e2 + e3);
#pragma unroll
        for (int msk = 1; msk < 16; msk <<= 1) sm += __shfl_xor(sm, msk, 64);
        const float inv = 1.f / sm;
        unsigned short* wp = wa + (plbase + q * 4 + r) * 72 + r16;
        wp[0]  = f2bf(e0 * inv);
        wp[16] = f2bf(e1 * inv);
        wp[32] = f2bf(e2 * inv);
        wp[48] = f2bf(e3 * inv);
    }

    // ---- W A-frags from LDS (A[px=r16][kk = 32s + 8q + j]) ----
    bf16x8 af[2];
#pragma unroll
    for (int s = 0; s < 2; s++)
        af[s] = *(const bf16x8*)(wa + (plbase + r16) * 72 + 32 * s + q * 8);

    // ---- GEMM2 + residual epilogue (float4) ----
    float* ob = out + (size_t)b * (C_L_ * NPIX_L);
#pragma unroll
    for (int nc = 0; nc < 4; nc++) {
        f32x4 acc2[4] = {};
#pragma unroll
        for (int s = 0; s < 2; s++) {
            const bf16x8* bp2 = ((const bf16x8*)b2) + ((b * 2 + s) * 16 + nc * 4) * 64 + lane;
#pragma unroll
            for (int nn = 0; nn < 4; nn++) {
                const bf16x8 bfr = bp2[nn * 64];
                acc2[nn] = MFMA16(af[s], bfr, acc2[nn]);
            }
        }
#pragma unroll
        for (int nn = 0; nn < 4; nn++) {
            const int co = 16 * (nc * 4 + nn) + r16;
            const size_t base = (size_t)co * NPIX_L + pw0 + q * 4;
            const float4 xv4 = *reinterpret_cast<const float4*>(xb + base);
            float4 o;
            o.x = acc2[nn][0] + xv4.x;
            o.y = acc2[nn][1] + xv4.y;
            o.z = acc2[nn][2] + xv4.z;
            o.w = acc2[nn][3] + xv4.w;
            *reinterpret_cast<float4*>(ob + base) = o;
        }
    }
}

extern "C" void kernel_launch(void* const* d_in, const int* in_sizes, int n_in,
                              void* d_out, int out_size, void* d_ws, size_t ws_size,
                              hipStream_t stream) {
    const float* x_h  = (const float*)d_in[0];
    const float* x_l  = (const float*)d_in[1];
    const float* hg   = (const float*)d_in[2];
    const float* hb   = (const float*)d_in[3];
    const float* hm   = (const float*)d_in[4];
    const float* hv   = (const float*)d_in[5];
    const float* kvw  = (const float*)d_in[6];
    const float* kvb  = (const float*)d_in[7];
    const float* lg   = (const float*)d_in[8];
    const float* lb   = (const float*)d_in[9];
    const float* lm   = (const float*)d_in[10];
    const float* lv   = (const float*)d_in[11];
    const float* ratt = (const float*)d_in[12];
    float* ws  = (float*)d_ws;
    float* out = (float*)d_out;

    pool_bn_kernel<<<256, 256, 0, stream>>>(x_h, hg, hb, hm, hv, ws);
    kv_kernel<<<512, 256, 0, stream>>>(kvw, kvb, lg, lb, lm, lv, ratt, ws);
    attn_mfma<<<2048, 256, 0, stream>>>(x_l, ws, out);
}

// Round 3
// 306.627 us; speedup vs baseline: 1.1913x; 1.1913x over previous
//
#include <hip/hip_runtime.h>
#include <math.h>

#define B_     8
#define C_H_   128
#define C_L_   256
#define K_     64
#define NPIX_L 16384          // 128*128
#define EPS_   1e-5f

// ws layout: P (float) | B1 (bf16, swizzled) | B2 (bf16, swizzled) | bias (float)
#define P_OFF     0
#define P_SZ      (B_*K_*C_H_)                 // 65536 floats
#define B1_BYTE   (P_SZ*4)                     // 262144
#define B2_BYTE   (B1_BYTE + B_*K_*C_L_*2)     // +262144
#define BIAS_BYTE (B2_BYTE + B_*K_*C_L_*2)     // 512 floats

typedef short bf16x8 __attribute__((ext_vector_type(8)));   // 4 VGPRs = 8 bf16
typedef float f32x4  __attribute__((ext_vector_type(4)));

__device__ inline unsigned short f2bf(float f) {            // RNE fp32->bf16
    unsigned int u = __float_as_uint(f);
    u += 0x7FFFu + ((u >> 16) & 1u);
    return (unsigned short)(u >> 16);
}
__device__ inline unsigned int pack2bf(float lo, float hi) { // two bf16 in one u32
    unsigned int ul = __float_as_uint(lo);
    unsigned int uh = __float_as_uint(hi);
    ul = (ul + (0x7FFFu + ((ul >> 16) & 1u))) >> 16;
    uh = (uh + (0x7FFFu + ((uh >> 16) & 1u))) & 0xFFFF0000u;
    return ul | uh;
}

#define MFMA16(a, b, c) __builtin_amdgcn_mfma_f32_16x16x32_bf16((a), (b), (c), 0, 0, 0)

#define GLOAD_LDS16(g, l) __builtin_amdgcn_global_load_lds( \
    (const __attribute__((address_space(1))) void*)(g), \
    (__attribute__((address_space(3))) void*)(l), 16, 0, 0)

// ---------------- Kernel 1: BN + 8x8 max-pool of x_h -> p[b][k][c] ----------------
__global__ __launch_bounds__(256) void pool_bn_kernel(
    const float* __restrict__ x_h,
    const float* __restrict__ g, const float* __restrict__ be,
    const float* __restrict__ mn, const float* __restrict__ vr,
    float* __restrict__ ws)
{
    const int t   = threadIdx.x;
    const int k   = t & 63;
    const int cl  = t >> 6;
    const int bid = blockIdx.x;    // 256 = 8 b * 32 cgroups
    const int b   = bid >> 5;
    const int c   = ((bid & 31) << 2) + cl;

    const float* plane = x_h + ((size_t)(b * C_H_ + c) << 12);
    const int ph = k >> 3, pw = k & 7;
    const float* p0 = plane + (ph * 8) * 64 + pw * 8;

    float mx = -INFINITY, mnv = INFINITY;
#pragma unroll
    for (int i = 0; i < 8; i++) {
        const float4 a  = *reinterpret_cast<const float4*>(p0 + i * 64);
        const float4 bq = *reinterpret_cast<const float4*>(p0 + i * 64 + 4);
        mx  = fmaxf(mx,  fmaxf(fmaxf(a.x, a.y),  fmaxf(a.z, a.w)));
        mx  = fmaxf(mx,  fmaxf(fmaxf(bq.x, bq.y), fmaxf(bq.z, bq.w)));
        mnv = fminf(mnv, fminf(fminf(a.x, a.y),  fminf(a.z, a.w)));
        mnv = fminf(mnv, fminf(fminf(bq.x, bq.y), fminf(bq.z, bq.w)));
    }
    const float sc  = g[c] * rsqrtf(vr[c] + EPS_);
    const float sel = (sc >= 0.f) ? mx : mnv;
    ws[P_OFF + (b * K_ + k) * C_H_ + c] = fmaf(sel - mn[c], sc, be[c]);
}

// ---------------- Kernel 2: kv projection -> swizzled bf16 B1/B2 + softmax bias ----------------
__global__ __launch_bounds__(256) void kv_kernel(
    const float* __restrict__ kv_w, const float* __restrict__ kv_b,
    const float* __restrict__ lg, const float* __restrict__ lb,
    const float* __restrict__ lm, const float* __restrict__ lv,
    const float* __restrict__ ratt,
    float* __restrict__ ws)
{
    __shared__ __align__(16) float prow[C_H_];
    __shared__ float red[4];
    const int t   = threadIdx.x;
    const int bid = blockIdx.x;          // 512 = 8 b * 64 kk
    const int b   = bid >> 6;
    const int kk  = bid & 63;

    if (t < C_H_ / 4) {
        reinterpret_cast<float4*>(prow)[t] =
            reinterpret_cast<const float4*>(ws + P_OFF + (b * K_ + kk) * C_H_)[t];
    }
    __syncthreads();

    float a0 = kv_b[t];          // ck[b][kk][c=t]
    float a1 = kv_b[t + 256];    // cv[b][co=t][kk]
    const float* w0 = kv_w + (size_t)t * C_H_;
    const float* w1 = kv_w + (size_t)(t + 256) * C_H_;
#pragma unroll
    for (int c = 0; c < C_H_; c += 4) {
        const float4 pv  = *reinterpret_cast<const float4*>(prow + c);
        const float4 wv0 = *reinterpret_cast<const float4*>(w0 + c);
        const float4 wv1 = *reinterpret_cast<const float4*>(w1 + c);
        a0 = fmaf(wv0.x, pv.x, a0); a0 = fmaf(wv0.y, pv.y, a0);
        a0 = fmaf(wv0.z, pv.z, a0); a0 = fmaf(wv0.w, pv.w, a0);
        a1 = fmaf(wv1.x, pv.x, a1); a1 = fmaf(wv1.y, pv.y, a1);
        a1 = fmaf(wv1.z, pv.z, a1); a1 = fmaf(wv1.w, pv.w, a1);
    }

    const float s = lg[t] * rsqrtf(lv[t] + EPS_);
    const float h = fmaf(-lm[t], s, lb[t]);

    float contrib = h * a0;
#pragma unroll
    for (int m = 1; m < 64; m <<= 1) contrib += __shfl_xor(contrib, m, 64);
    if ((t & 63) == 0) red[t >> 6] = contrib;
    __syncthreads();

    unsigned short* b1 = (unsigned short*)((char*)ws + B1_BYTE);
    unsigned short* b2 = (unsigned short*)((char*)ws + B2_BYTE);

    {   // B1 swizzle: value at (c=t, kk)
        const int s1 = t >> 5, j = t & 7;
        const int l  = ((t >> 3) & 3) * 16 + (kk & 15);
        const int n  = kk >> 4;
        b1[((((b * 8 + s1) * 4 + n) * 64) + l) * 8 + j] = f2bf(a0 * s);
    }
    {   // B2 swizzle: value at (kk, co=t)
        const int s2 = kk >> 5, j2 = kk & 7;
        const int l2 = ((kk >> 3) & 3) * 16 + (t & 15);
        const int n2 = t >> 4;
        b2[((((b * 2 + s2) * 16 + n2) * 64) + l2) * 8 + j2] = f2bf(a1);
    }
    if (t == 0) {
        float* bia = (float*)((char*)ws + BIAS_BYTE);
        bia[b * K_ + kk] = (red[0] + red[1] + red[2] + red[3] + ratt[kk]) * 0.125f;
    }
}

// ---------------- Kernel 3: MFMA attention, contiguous-stream version ----------------
// 1024 blocks (b=bid&7), 256 threads = 4 waves, 128 px/block, 32 px/wave (2 m-tiles).
// GEMM1: x_l staged block-cooperatively into LDS via global_load_lds (512B/row
// contiguous, double-buffered, counted vmcnt(4) + raw barriers). Source px4-units
// pre-XORed by (q_c<<2) so frag scalar reads hit <=2-way banks (LDS stays linear).
// Epilogue: Out staged to LDS (32co x 128px, stride 132w) then cooperative
// 512B-contiguous float4 residual-read + store.
__global__ __launch_bounds__(256, 4) void attn_mfma(
    const float* __restrict__ x_l,
    const float* __restrict__ ws_f,
    float* __restrict__ out)
{
    // [0,16384) XBUF0 | [16384,32768) XBUF1 | OUTBUF [16384,33280) (after GEMM1)
    // Wscratch [0,9216) per-wave 16 rows x 72 shorts (after GEMM1)
    __shared__ __align__(16) char lds[33280];
    float* xbuf0 = (float*)lds;                       // [32][128] fp32
    float* xbuf1 = (float*)(lds + 16384);
    unsigned short* wscr = (unsigned short*)lds;
    float* obuf = (float*)(lds + 16384);              // [32][132] fp32

    const int t    = threadIdx.x;
    const int lane = t & 63;
    const int wid  = t >> 6;                  // 0..3
    const int bid  = blockIdx.x;
    const int b    = bid & 7;
    const int tile = bid >> 3;                // 0..127
    const int px0  = tile * 128;              // block pixel base
    const int pxw  = wid * 32;                // wave pixel base within block
    const int r16  = lane & 15;
    const int q    = lane >> 4;

    const unsigned short* b1 = (const unsigned short*)((const char*)ws_f + B1_BYTE);
    const unsigned short* b2 = (const unsigned short*)((const char*)ws_f + B2_BYTE);
    const float* biasf = (const float*)((const char*)ws_f + BIAS_BYTE) + b * K_;
    const float* xb = x_l + (size_t)b * (C_L_ * NPIX_L);
    float* ob = out + (size_t)b * (C_L_ * NPIX_L);

    float bl[4];
#pragma unroll
    for (int n = 0; n < 4; n++) bl[n] = biasf[16 * n + r16];

    // staging: wave stages rows c_local = 8*wid .. 8*wid+7 (q_c = wid for all),
    // per call 2 rows (1KB), lane's global 16B-unit pre-XORed by (wid<<2).
    const int su = ((lane & 31) ^ (wid << 2)) << 2;   // float offset in row
    const int sd = lane >> 5;                         // row delta within call
#define STAGE(bufp, s_) do { \
    _Pragma("unroll") \
    for (int i_ = 0; i_ < 4; i_++) { \
        const int cl_ = 8 * wid + 2 * i_; \
        const float* gp_ = xb + (size_t)(32 * (s_) + cl_ + sd) * NPIX_L + px0 + su; \
        GLOAD_LDS16(gp_, (bufp) + (size_t)cl_ * 128); \
    } \
} while (0)

    // ---- GEMM1: double-buffered staged chunks of 32 channels ----
    f32x4 acc1[2][4] = {};
    union ABu { bf16x8 v; unsigned int u[4]; };

    STAGE(xbuf0, 0);

    const int p0x = (pxw + r16) ^ (q << 4);        // swizzled LDS col, m=0
    const int p1x = (pxw + 16 + r16) ^ (q << 4);   // m=1

#pragma unroll
    for (int s = 0; s < 8; s++) {
        float* xbf = (s & 1) ? xbuf1 : xbuf0;
        if (s < 7) {
            STAGE((s & 1) ? xbuf0 : xbuf1, s + 1);
            asm volatile("s_waitcnt vmcnt(4)" ::: "memory");
        } else {
            asm volatile("s_waitcnt vmcnt(0)" ::: "memory");
        }
        __builtin_amdgcn_s_barrier();   // chunk s visible block-wide

        ABu a0f, a1f;
#pragma unroll
        for (int jj = 0; jj < 4; jj++) {
            const float* row0 = xbf + (8 * q + 2 * jj) * 128;
            const float* row1 = xbf + (8 * q + 2 * jj + 1) * 128;
            a0f.u[jj] = pack2bf(row0[p0x], row1[p0x]);
            a1f.u[jj] = pack2bf(row0[p1x], row1[p1x]);
        }
        const bf16x8* bp = ((const bf16x8*)b1) + ((b * 8 + s) * 4) * 64 + lane;
#pragma unroll
        for (int n = 0; n < 4; n++) {
            const bf16x8 bfr = bp[n * 64];
            acc1[0][n] = MFMA16(a0f.v, bfr, acc1[0][n]);
            acc1[1][n] = MFMA16(a1f.v, bfr, acc1[1][n]);
        }
        __builtin_amdgcn_s_barrier();   // all waves done with buf before overwrite
    }

    // ---- softmax + W -> per-wave scratch -> A-frags (staggered m=0, m=1) ----
    unsigned short* wsb = wscr + wid * 1152;   // 16 rows x 72 shorts
    bf16x8 af[2][2];
#pragma unroll
    for (int m = 0; m < 2; m++) {
#pragma unroll
        for (int r = 0; r < 4; r++) {
            float e0 = fmaf(acc1[m][0][r], 0.125f, bl[0]);
            float e1 = fmaf(acc1[m][1][r], 0.125f, bl[1]);
            float e2 = fmaf(acc1[m][2][r], 0.125f, bl[2]);
            float e3 = fmaf(acc1[m][3][r], 0.125f, bl[3]);
            float mx = fmaxf(fmaxf(e0, e1), fmaxf(e2, e3));
#pragma unroll
            for (int msk = 1; msk < 16; msk <<= 1) mx = fmaxf(mx, __shfl_xor(mx, msk, 64));
            e0 = __expf(e0 - mx); e1 = __expf(e1 - mx);
            e2 = __expf(e2 - mx); e3 = __expf(e3 - mx);
            float sm = (e0 + e1) + (e2 + e3);
#pragma unroll
            for (int msk = 1; msk < 16; msk <<= 1) sm += __shfl_xor(sm, msk, 64);
            const float inv = 1.f / sm;
            unsigned short* wp = wsb + (q * 4 + r) * 72 + r16;
            wp[0]  = f2bf(e0 * inv);
            wp[16] = f2bf(e1 * inv);
            wp[32] = f2bf(e2 * inv);
            wp[48] = f2bf(e3 * inv);
        }
#pragma unroll
        for (int s2 = 0; s2 < 2; s2++)
            af[m][s2] = *(const bf16x8*)(wsb + r16 * 72 + 32 * s2 + q * 8);
        if (m == 0) asm volatile("s_waitcnt lgkmcnt(0)" ::: "memory"); // drain reads before overwrite
    }

    // ---- GEMM2 + LDS-transposed epilogue (contiguous stores + residual) ----
#pragma unroll
    for (int nc = 0; nc < 4; nc++) {
        f32x4 acc2[2][4] = {};
#pragma unroll
        for (int s2 = 0; s2 < 2; s2++) {
            const bf16x8* bp2 = ((const bf16x8*)b2) + ((b * 2 + s2) * 16 + nc * 4) * 64 + lane;
#pragma unroll
            for (int nn = 0; nn < 4; nn++) {
                const bf16x8 bfr = bp2[nn * 64];
                acc2[0][nn] = MFMA16(af[0][s2], bfr, acc2[0][nn]);
                acc2[1][nn] = MFMA16(af[1][s2], bfr, acc2[1][nn]);
            }
        }
#pragma unroll
        for (int h = 0; h < 2; h++) {
            // deposit acc2[m][2h+e] at obuf[16e+r16][pxw+16m+4q..+3]
#pragma unroll
            for (int m = 0; m < 2; m++)
#pragma unroll
                for (int e = 0; e < 2; e++) {
                    float* dp = obuf + (16 * e + r16) * 132 + (pxw + 16 * m + 4 * q);
                    *(f32x4*)dp = acc2[m][2 * h + e];
                }
            asm volatile("s_waitcnt lgkmcnt(0)" ::: "memory"); // writes done before barrier
            __builtin_amdgcn_s_barrier();
            const int cbase = 64 * nc + 32 * h;
#pragma unroll
            for (int u2 = 0; u2 < 4; u2++) {
                const int idx = t + 256 * u2;      // 0..1023
                const int col = idx >> 5;          // co_local 0..31
                const int un  = idx & 31;          // 16B-unit within row
                const float4 vv = *(const float4*)(obuf + col * 132 + un * 4);
                const size_t gbase = (size_t)(cbase + col) * NPIX_L + px0 + un * 4;
                const float4 xv4 = *(const float4*)(xb + gbase);
                float4 o;
                o.x = vv.x + xv4.x; o.y = vv.y + xv4.y;
                o.z = vv.z + xv4.z; o.w = vv.w + xv4.w;
                *(float4*)(ob + gbase) = o;
            }
            __builtin_amdgcn_s_barrier();          // reads done before next deposit
        }
    }
#undef STAGE
}

extern "C" void kernel_launch(void* const* d_in, const int* in_sizes, int n_in,
                              void* d_out, int out_size, void* d_ws, size_t ws_size,
                              hipStream_t stream) {
    const float* x_h  = (const float*)d_in[0];
    const float* x_l  = (const float*)d_in[1];
    const float* hg   = (const float*)d_in[2];
    const float* hb   = (const float*)d_in[3];
    const float* hm   = (const float*)d_in[4];
    const float* hv   = (const float*)d_in[5];
    const float* kvw  = (const float*)d_in[6];
    const float* kvb  = (const float*)d_in[7];
    const float* lg   = (const float*)d_in[8];
    const float* lb   = (const float*)d_in[9];
    const float* lm   = (const float*)d_in[10];
    const float* lv   = (const float*)d_in[11];
    const float* ratt = (const float*)d_in[12];
    float* ws  = (float*)d_ws;
    float* out = (float*)d_out;

    pool_bn_kernel<<<256, 256, 0, stream>>>(x_h, hg, hb, hm, hv, ws);
    kv_kernel<<<512, 256, 0, stream>>>(kvw, kvb, lg, lb, lm, lv, ratt, ws);
    attn_mfma<<<1024, 256, 0, stream>>>(x_l, ws, out);
}

// Round 4
// 302.660 us; speedup vs baseline: 1.2069x; 1.0131x over previous
//
#include <hip/hip_runtime.h>
#include <math.h>

#define B_     8
#define C_H_   128
#define C_L_   256
#define K_     64
#define NPIX_L 16384          // 128*128
#define EPS_   1e-5f

// ws layout: P (float) | B1 (bf16, swizzled) | B2 (bf16, swizzled) | bias (float)
#define P_OFF     0
#define P_SZ      (B_*K_*C_H_)                 // 65536 floats
#define B1_BYTE   (P_SZ*4)                     // 262144
#define B2_BYTE   (B1_BYTE + B_*K_*C_L_*2)     // +262144
#define BIAS_BYTE (B2_BYTE + B_*K_*C_L_*2)     // 512 floats

typedef short bf16x8 __attribute__((ext_vector_type(8)));   // 4 VGPRs = 8 bf16
typedef float f32x4  __attribute__((ext_vector_type(4)));

__device__ inline unsigned short f2bf(float f) {            // RNE fp32->bf16
    unsigned int u = __float_as_uint(f);
    u += 0x7FFFu + ((u >> 16) & 1u);
    return (unsigned short)(u >> 16);
}
__device__ inline unsigned int pack2bf(float lo, float hi) { // two bf16 in one u32
    unsigned int ul = __float_as_uint(lo);
    unsigned int uh = __float_as_uint(hi);
    ul = (ul + (0x7FFFu + ((ul >> 16) & 1u))) >> 16;
    uh = (uh + (0x7FFFu + ((uh >> 16) & 1u))) & 0xFFFF0000u;
    return ul | uh;
}

#define MFMA16(a, b, c) __builtin_amdgcn_mfma_f32_16x16x32_bf16((a), (b), (c), 0, 0, 0)

#define GLOAD_LDS16(g, l) __builtin_amdgcn_global_load_lds( \
    (const __attribute__((address_space(1))) void*)(g), \
    (__attribute__((address_space(3))) void*)(l), 16, 0, 0)

// ---------------- Kernel 1: BN + 8x8 max-pool of x_h -> p[b][k][c] ----------------
__global__ __launch_bounds__(256) void pool_bn_kernel(
    const float* __restrict__ x_h,
    const float* __restrict__ g, const float* __restrict__ be,
    const float* __restrict__ mn, const float* __restrict__ vr,
    float* __restrict__ ws)
{
    const int t   = threadIdx.x;
    const int k   = t & 63;
    const int cl  = t >> 6;
    const int bid = blockIdx.x;    // 256 = 8 b * 32 cgroups
    const int b   = bid >> 5;
    const int c   = ((bid & 31) << 2) + cl;

    const float* plane = x_h + ((size_t)(b * C_H_ + c) << 12);
    const int ph = k >> 3, pw = k & 7;
    const float* p0 = plane + (ph * 8) * 64 + pw * 8;

    float mx = -INFINITY, mnv = INFINITY;
#pragma unroll
    for (int i = 0; i < 8; i++) {
        const float4 a  = *reinterpret_cast<const float4*>(p0 + i * 64);
        const float4 bq = *reinterpret_cast<const float4*>(p0 + i * 64 + 4);
        mx  = fmaxf(mx,  fmaxf(fmaxf(a.x, a.y),  fmaxf(a.z, a.w)));
        mx  = fmaxf(mx,  fmaxf(fmaxf(bq.x, bq.y), fmaxf(bq.z, bq.w)));
        mnv = fminf(mnv, fminf(fminf(a.x, a.y),  fminf(a.z, a.w)));
        mnv = fminf(mnv, fminf(fminf(bq.x, bq.y), fminf(bq.z, bq.w)));
    }
    const float sc  = g[c] * rsqrtf(vr[c] + EPS_);
    const float sel = (sc >= 0.f) ? mx : mnv;
    ws[P_OFF + (b * K_ + k) * C_H_ + c] = fmaf(sel - mn[c], sc, be[c]);
}

// ---------------- Kernel 2: kv projection (coalesced rewrite) ----------------
// 256 blocks = 8 b * 16 kk-groups(4 px) * 2 output-halves. 256 threads.
// p (4 rows) in LDS (pad 132 -> broadcast, conflict-free). Quad (q4=t&3) of
// threads covers one output row o with interleaved c-partition c=i*16+q4*4+r:
// each w-load instruction = 16 consecutive rows x 64B -> 4 lanes/line (full
// line use, 16 probes vs 64 in old per-lane-row version). Quad shfl-reduce.
// Same B1/B2/bias swizzle formulas as before, fp32 math.
__global__ __launch_bounds__(256) void kv_kernel(
    const float* __restrict__ kv_w, const float* __restrict__ kv_b,
    const float* __restrict__ lg, const float* __restrict__ lb,
    const float* __restrict__ lm, const float* __restrict__ lv,
    const float* __restrict__ ratt,
    float* __restrict__ ws)
{
    __shared__ __align__(16) float plds[4 * 132];
    __shared__ float red[4][4];
    const int t    = threadIdx.x;
    const int lane = t & 63;
    const int wid  = t >> 6;
    const int bid  = blockIdx.x;        // 256 = b(8) * kg(16) * oh(2)
    const int b    = bid >> 5;
    const int kg   = (bid >> 1) & 15;
    const int oh   = bid & 1;

    if (t < 128) {                       // stage p: 4 rows x 128 floats
        const int px = t >> 5, u = t & 31;
        const float4 v = *reinterpret_cast<const float4*>(
            ws + P_OFF + (size_t)(b * K_ + kg * 4 + px) * C_H_ + u * 4);
        *reinterpret_cast<float4*>(plds + px * 132 + u * 4) = v;
    }
    __syncthreads();

    const int oi = t >> 2;               // 0..63
    const int q4 = t & 3;
    const int kk = kg * 4 + q4;

    unsigned short* b1 = (unsigned short*)((char*)ws + B1_BYTE);
    unsigned short* b2 = (unsigned short*)((char*)ws + B2_BYTE);

    float bc = 0.f;
#pragma unroll
    for (int pass = 0; pass < 4; pass++) {
        const int o = oh * 256 + pass * 64 + oi;
        const float* wrow = kv_w + (size_t)o * C_H_ + q4 * 4;
        float a0 = 0.f, a1 = 0.f, a2 = 0.f, a3 = 0.f;
#pragma unroll
        for (int i = 0; i < 8; i++) {
            const float4 wf = *reinterpret_cast<const float4*>(wrow + i * 16);
            const float4 p0 = *reinterpret_cast<const float4*>(plds + 0 * 132 + i * 16 + q4 * 4);
            const float4 p1 = *reinterpret_cast<const float4*>(plds + 1 * 132 + i * 16 + q4 * 4);
            const float4 p2 = *reinterpret_cast<const float4*>(plds + 2 * 132 + i * 16 + q4 * 4);
            const float4 p3 = *reinterpret_cast<const float4*>(plds + 3 * 132 + i * 16 + q4 * 4);
            a0 = fmaf(wf.x, p0.x, a0); a0 = fmaf(wf.y, p0.y, a0);
            a0 = fmaf(wf.z, p0.z, a0); a0 = fmaf(wf.w, p0.w, a0);
            a1 = fmaf(wf.x, p1.x, a1); a1 = fmaf(wf.y, p1.y, a1);
            a1 = fmaf(wf.z, p1.z, a1); a1 = fmaf(wf.w, p1.w, a1);
            a2 = fmaf(wf.x, p2.x, a2); a2 = fmaf(wf.y, p2.y, a2);
            a2 = fmaf(wf.z, p2.z, a2); a2 = fmaf(wf.w, p2.w, a2);
            a3 = fmaf(wf.x, p3.x, a3); a3 = fmaf(wf.y, p3.y, a3);
            a3 = fmaf(wf.z, p3.z, a3); a3 = fmaf(wf.w, p3.w, a3);
        }
        // quad butterfly: every lane gets full dot for each px
        a0 += __shfl_xor(a0, 1, 64); a0 += __shfl_xor(a0, 2, 64);
        a1 += __shfl_xor(a1, 1, 64); a1 += __shfl_xor(a1, 2, 64);
        a2 += __shfl_xor(a2, 1, 64); a2 += __shfl_xor(a2, 2, 64);
        a3 += __shfl_xor(a3, 1, 64); a3 += __shfl_xor(a3, 2, 64);
        float val = (q4 == 0) ? a0 : (q4 == 1) ? a1 : (q4 == 2) ? a2 : a3;
        val += kv_b[o];

        if (oh == 0) {   // ck path: channel c=o, plus bias contribution
            const float s = lg[o] * rsqrtf(lv[o] + EPS_);
            const float h = fmaf(-lm[o], s, lb[o]);
            bc = fmaf(h, val, bc);
            const int s1 = o >> 5, j = o & 7;
            const int l  = ((o >> 3) & 3) * 16 + (kk & 15);
            const int n  = kk >> 4;
            b1[((((b * 8 + s1) * 4 + n) * 64) + l) * 8 + j] = f2bf(val * s);
        } else {         // cv path: co = o-256
            const int co = o - 256;
            const int s2 = kk >> 5, j2 = kk & 7;
            const int l2 = ((kk >> 3) & 3) * 16 + (co & 15);
            const int n2 = co >> 4;
            b2[((((b * 2 + s2) * 16 + n2) * 64) + l2) * 8 + j2] = f2bf(val);
        }
    }

    if (oh == 0) {
        // reduce bc over the 16 lanes sharing q4 within each wave
#pragma unroll
        for (int m = 4; m < 64; m <<= 1) bc += __shfl_xor(bc, m, 64);
        if (lane < 4) red[wid][lane] = bc;
        __syncthreads();
        if (t < 4) {
            const float sum = red[0][t] + red[1][t] + red[2][t] + red[3][t];
            const int kkf = kg * 4 + t;
            float* bia = (float*)((char*)ws + BIAS_BYTE);
            bia[b * K_ + kkf] = (sum + ratt[kkf]) * 0.125f;
        }
    }
}

// ---------------- Kernel 3: MFMA attention, contiguous-stream version ----------------
// (unchanged from R3: 97.8 us, FETCH/WRITE = 1x minimal traffic)
__global__ __launch_bounds__(256, 4) void attn_mfma(
    const float* __restrict__ x_l,
    const float* __restrict__ ws_f,
    float* __restrict__ out)
{
    __shared__ __align__(16) char lds[33280];
    float* xbuf0 = (float*)lds;                       // [32][128] fp32
    float* xbuf1 = (float*)(lds + 16384);
    unsigned short* wscr = (unsigned short*)lds;
    float* obuf = (float*)(lds + 16384);              // [32][132] fp32

    const int t    = threadIdx.x;
    const int lane = t & 63;
    const int wid  = t >> 6;                  // 0..3
    const int bid  = blockIdx.x;
    const int b    = bid & 7;
    const int tile = bid >> 3;                // 0..127
    const int px0  = tile * 128;              // block pixel base
    const int pxw  = wid * 32;                // wave pixel base within block
    const int r16  = lane & 15;
    const int q    = lane >> 4;

    const unsigned short* b1 = (const unsigned short*)((const char*)ws_f + B1_BYTE);
    const unsigned short* b2 = (const unsigned short*)((const char*)ws_f + B2_BYTE);
    const float* biasf = (const float*)((const char*)ws_f + BIAS_BYTE) + b * K_;
    const float* xb = x_l + (size_t)b * (C_L_ * NPIX_L);
    float* ob = out + (size_t)b * (C_L_ * NPIX_L);

    float bl[4];
#pragma unroll
    for (int n = 0; n < 4; n++) bl[n] = biasf[16 * n + r16];

    const int su = ((lane & 31) ^ (wid << 2)) << 2;   // float offset in row
    const int sd = lane >> 5;                         // row delta within call
#define STAGE(bufp, s_) do { \
    _Pragma("unroll") \
    for (int i_ = 0; i_ < 4; i_++) { \
        const int cl_ = 8 * wid + 2 * i_; \
        const float* gp_ = xb + (size_t)(32 * (s_) + cl_ + sd) * NPIX_L + px0 + su; \
        GLOAD_LDS16(gp_, (bufp) + (size_t)cl_ * 128); \
    } \
} while (0)

    // ---- GEMM1: double-buffered staged chunks of 32 channels ----
    f32x4 acc1[2][4] = {};
    union ABu { bf16x8 v; unsigned int u[4]; };

    STAGE(xbuf0, 0);

    const int p0x = (pxw + r16) ^ (q << 4);        // swizzled LDS col, m=0
    const int p1x = (pxw + 16 + r16) ^ (q << 4);   // m=1

#pragma unroll
    for (int s = 0; s < 8; s++) {
        float* xbf = (s & 1) ? xbuf1 : xbuf0;
        if (s < 7) {
            STAGE((s & 1) ? xbuf0 : xbuf1, s + 1);
            asm volatile("s_waitcnt vmcnt(4)" ::: "memory");
        } else {
            asm volatile("s_waitcnt vmcnt(0)" ::: "memory");
        }
        __builtin_amdgcn_s_barrier();   // chunk s visible block-wide

        ABu a0f, a1f;
#pragma unroll
        for (int jj = 0; jj < 4; jj++) {
            const float* row0 = xbf + (8 * q + 2 * jj) * 128;
            const float* row1 = xbf + (8 * q + 2 * jj + 1) * 128;
            a0f.u[jj] = pack2bf(row0[p0x], row1[p0x]);
            a1f.u[jj] = pack2bf(row0[p1x], row1[p1x]);
        }
        const bf16x8* bp = ((const bf16x8*)b1) + ((b * 8 + s) * 4) * 64 + lane;
#pragma unroll
        for (int n = 0; n < 4; n++) {
            const bf16x8 bfr = bp[n * 64];
            acc1[0][n] = MFMA16(a0f.v, bfr, acc1[0][n]);
            acc1[1][n] = MFMA16(a1f.v, bfr, acc1[1][n]);
        }
        __builtin_amdgcn_s_barrier();   // all waves done with buf before overwrite
    }

    // ---- softmax + W -> per-wave scratch -> A-frags (staggered m=0, m=1) ----
    unsigned short* wsb = wscr + wid * 1152;   // 16 rows x 72 shorts
    bf16x8 af[2][2];
#pragma unroll
    for (int m = 0; m < 2; m++) {
#pragma unroll
        for (int r = 0; r < 4; r++) {
            float e0 = fmaf(acc1[m][0][r], 0.125f, bl[0]);
            float e1 = fmaf(acc1[m][1][r], 0.125f, bl[1]);
            float e2 = fmaf(acc1[m][2][r], 0.125f, bl[2]);
            float e3 = fmaf(acc1[m][3][r], 0.125f, bl[3]);
            float mx = fmaxf(fmaxf(e0, e1), fmaxf(e2, e3));
#pragma unroll
            for (int msk = 1; msk < 16; msk <<= 1) mx = fmaxf(mx, __shfl_xor(mx, msk, 64));
            e0 = __expf(e0 - mx); e1 = __expf(e1 - mx);
            e2 = __expf(e2 - mx); e3 = __expf(e3 - mx);
            float sm = (e0 + e1) + (e2 + e3);
#pragma unroll
            for (int msk = 1; msk < 16; msk <<= 1) sm += __shfl_xor(sm, msk, 64);
            const float inv = 1.f / sm;
            unsigned short* wp = wsb + (q * 4 + r) * 72 + r16;
            wp[0]  = f2bf(e0 * inv);
            wp[16] = f2bf(e1 * inv);
            wp[32] = f2bf(e2 * inv);
            wp[48] = f2bf(e3 * inv);
        }
#pragma unroll
        for (int s2 = 0; s2 < 2; s2++)
            af[m][s2] = *(const bf16x8*)(wsb + r16 * 72 + 32 * s2 + q * 8);
        if (m == 0) asm volatile("s_waitcnt lgkmcnt(0)" ::: "memory"); // drain reads before overwrite
    }

    // ---- GEMM2 + LDS-transposed epilogue (contiguous stores + residual) ----
#pragma unroll
    for (int nc = 0; nc < 4; nc++) {
        f32x4 acc2[2][4] = {};
#pragma unroll
        for (int s2 = 0; s2 < 2; s2++) {
            const bf16x8* bp2 = ((const bf16x8*)b2) + ((b * 2 + s2) * 16 + nc * 4) * 64 + lane;
#pragma unroll
            for (int nn = 0; nn < 4; nn++) {
                const bf16x8 bfr = bp2[nn * 64];
                acc2[0][nn] = MFMA16(af[0][s2], bfr, acc2[0][nn]);
                acc2[1][nn] = MFMA16(af[1][s2], bfr, acc2[1][nn]);
            }
        }
#pragma unroll
        for (int h = 0; h < 2; h++) {
#pragma unroll
            for (int m = 0; m < 2; m++)
#pragma unroll
                for (int e = 0; e < 2; e++) {
                    float* dp = obuf + (16 * e + r16) * 132 + (pxw + 16 * m + 4 * q);
                    *(f32x4*)dp = acc2[m][2 * h + e];
                }
            asm volatile("s_waitcnt lgkmcnt(0)" ::: "memory"); // writes done before barrier
            __builtin_amdgcn_s_barrier();
            const int cbase = 64 * nc + 32 * h;
#pragma unroll
            for (int u2 = 0; u2 < 4; u2++) {
                const int idx = t + 256 * u2;      // 0..1023
                const int col = idx >> 5;          // co_local 0..31
                const int un  = idx & 31;          // 16B-unit within row
                const float4 vv = *(const float4*)(obuf + col * 132 + un * 4);
                const size_t gbase = (size_t)(cbase + col) * NPIX_L + px0 + un * 4;
                const float4 xv4 = *(const float4*)(xb + gbase);
                float4 o;
                o.x = vv.x + xv4.x; o.y = vv.y + xv4.y;
                o.z = vv.z + xv4.z; o.w = vv.w + xv4.w;
                *(float4*)(ob + gbase) = o;
            }
            __builtin_amdgcn_s_barrier();          // reads done before next deposit
        }
    }
#undef STAGE
}

extern "C" void kernel_launch(void* const* d_in, const int* in_sizes, int n_in,
                              void* d_out, int out_size, void* d_ws, size_t ws_size,
                              hipStream_t stream) {
    const float* x_h  = (const float*)d_in[0];
    const float* x_l  = (const float*)d_in[1];
    const float* hg   = (const float*)d_in[2];
    const float* hb   = (const float*)d_in[3];
    const float* hm   = (const float*)d_in[4];
    const float* hv   = (const float*)d_in[5];
    const float* kvw  = (const float*)d_in[6];
    const float* kvb  = (const float*)d_in[7];
    const float* lg   = (const float*)d_in[8];
    const float* lb   = (const float*)d_in[9];
    const float* lm   = (const float*)d_in[10];
    const float* lv   = (const float*)d_in[11];
    const float* ratt = (const float*)d_in[12];
    float* ws  = (float*)d_ws;
    float* out = (float*)d_out;

    pool_bn_kernel<<<256, 256, 0, stream>>>(x_h, hg, hb, hm, hv, ws);
    kv_kernel<<<256, 256, 0, stream>>>(kvw, kvb, lg, lb, lm, lv, ratt, ws);
    attn_mfma<<<1024, 256, 0, stream>>>(x_l, ws, out);
}